// Round 22
// baseline (2943.248 us; speedup 1.0000x reference)
//
#include <hip/hip_runtime.h>

#define BDIM 64
#define TDIM 1024
#define DDIM 256
#define HDIM 512
#define RING 4

typedef unsigned short ushort_t;
typedef unsigned int uint32;
typedef unsigned long long ull;
typedef __attribute__((ext_vector_type(8))) short short8;
typedef __attribute__((ext_vector_type(4))) float f32x4;
typedef __attribute__((ext_vector_type(4))) uint32 u32x4;

__device__ __forceinline__ ushort_t f2bf(float f) {
  union { float f; uint32 u; } v; v.f = f;
  uint32 u = v.u;
  return (ushort_t)((u + 0x7fffu + ((u >> 16) & 1u)) >> 16);
}

__device__ __forceinline__ short8 pack8(float4 a, float4 b) {
  short8 s;
  s[0] = (short)f2bf(a.x); s[1] = (short)f2bf(a.y);
  s[2] = (short)f2bf(a.z); s[3] = (short)f2bf(a.w);
  s[4] = (short)f2bf(b.x); s[5] = (short)f2bf(b.y);
  s[6] = (short)f2bf(b.z); s[7] = (short)f2bf(b.w);
  return s;
}

__device__ __forceinline__ ull pack4bf(f32x4 v) {
  return (ull)f2bf(v[0]) | ((ull)f2bf(v[1]) << 16)
       | ((ull)f2bf(v[2]) << 32) | ((ull)f2bf(v[3]) << 48);
}

__device__ __forceinline__ float sigm(float x) { return 1.0f / (1.0f + __expf(-x)); }
__device__ __forceinline__ float tanh_fast(float x) { return 1.0f - 2.0f / (__expf(2.0f * x) + 1.0f); }

__device__ __forceinline__ uint32 ld_sc1(uint32* p) {
  return __hip_atomic_load(p, __ATOMIC_RELAXED, __HIP_MEMORY_SCOPE_AGENT);
}
__device__ __forceinline__ void st_sc1(uint32* p, uint32 v) {
  __hip_atomic_store(p, v, __ATOMIC_RELAXED, __HIP_MEMORY_SCOPE_AGENT);
}

__device__ __forceinline__ void wave_poll_sc1(uint32* fl, uint32 tgt) {
  int it = 0;
  for (;;) {
    uint32 v = ld_sc1(fl);
    if (__all((int)(v >= tgt))) break;
    __builtin_amdgcn_s_sleep(1);
    if (++it > 60000) break;   // bounded: wrong beats hang
  }
  asm volatile("" ::: "memory");
}

// ---- fragment-major LDS layout (conflict-free MFMA reads, r10/r14-proven) ----
__device__ __forceinline__ int frag_off(int row, int kf, int lg) {   // ushort units
  return kf * 512 + (((lg * 16 + row) ^ (kf & 7)) << 3);
}

// ---- r14 lane-permuted staging map: conflict-free b64 LDS writes ----
__device__ __forceinline__ void ds_stage(ushort_t* dst, int tid, const ull* v) {
  const int s = tid & 15, h = (tid >> 4) & 3, wvq = tid >> 6;
#pragma unroll
  for (int q = 0; q < 8; ++q) {
    const int row = wvq * 4 + (q & 3);
    const int kf  = ((q >> 2) << 3) | ((s >> 1) & 7);
    *(ull*)&dst[frag_off(row, kf, h) + (s & 1) * 4] = v[q];
  }
}

// chunk offset within a bt tile for this thread (r14 index space, 16B chunks)
__device__ __forceinline__ size_t chunk_off(int tid) {
  const int s = tid & 15, h = (tid >> 4) & 3, wvq = tid >> 6;
  return (size_t)(wvq * 4) * 2048
       + (size_t)(((((s >> 1) & 7) * 8) + h * 2 + (s & 1)) * 16);
}

// ---- tag-fused tile load: 16B chunks [h:8B][tag:4B][pad:4B], spin per-thread ----
__device__ __forceinline__ void load_tagged_8(const char* buf, int tid, uint32 expect, ull* v) {
  const char* base  = buf + chunk_off(tid);
  const char* base2 = base + 4096;
  u32x4 c0, c1, c2, c3, c4v, c5, c6, c7;
  int it = 0;
  for (;;) {
    asm volatile(
        "global_load_dwordx4 %0, %8, off sc0 sc1\n\t"
        "global_load_dwordx4 %1, %8, off offset:1024 sc0 sc1\n\t"
        "global_load_dwordx4 %2, %8, off offset:2048 sc0 sc1\n\t"
        "global_load_dwordx4 %3, %8, off offset:3072 sc0 sc1\n\t"
        "global_load_dwordx4 %4, %9, off sc0 sc1\n\t"
        "global_load_dwordx4 %5, %9, off offset:1024 sc0 sc1\n\t"
        "global_load_dwordx4 %6, %9, off offset:2048 sc0 sc1\n\t"
        "global_load_dwordx4 %7, %9, off offset:3072 sc0 sc1\n\t"
        "s_waitcnt vmcnt(0)"
        : "=&v"(c0), "=&v"(c1), "=&v"(c2), "=&v"(c3),
          "=&v"(c4v), "=&v"(c5), "=&v"(c6), "=&v"(c7)
        : "v"(base), "v"(base2) : "memory");
    bool ok = (c0.z == expect) & (c1.z == expect) & (c2.z == expect) & (c3.z == expect)
            & (c4v.z == expect) & (c5.z == expect) & (c6.z == expect) & (c7.z == expect);
    if (ok) break;
    if (++it > 30000) break;   // bounded: wrong beats hang
  }
  v[0] = ((ull)c0.y << 32) | c0.x;   v[4] = ((ull)c1.y << 32) | c1.x;
  v[1] = ((ull)c2.y << 32) | c2.x;   v[5] = ((ull)c3.y << 32) | c3.x;
  v[2] = ((ull)c4v.y << 32) | c4v.x; v[6] = ((ull)c5.y << 32) | c5.x;
  v[3] = ((ull)c6.y << 32) | c6.x;   v[7] = ((ull)c7.y << 32) | c7.x;
}

#define BT_BYTES   32768            // 16 rows x 128 chunks x 16B
#define SLOT_BYTES (4 * BT_BYTES)   // 4 bt tiles

__global__ void __launch_bounds__(256, 1)
lstm_fused(const float* __restrict__ x,
           const float* __restrict__ w_ih0, const float* __restrict__ w_hh0,
           const float* __restrict__ b0,
           const float* __restrict__ w_ih1, const float* __restrict__ w_hh1,
           const float* __restrict__ b1,
           float* __restrict__ out,
           uint32* consF, char* ringT, char* h1T)
{
  const int b     = (int)blockIdx.x;
  const int g     = b & 7;
  const int layer = g >> 2;
  const int bt    = g & 3;
  const int ct    = b >> 3;
  const int tid   = (int)threadIdx.x;
  const int wv    = tid >> 6;
  const int lane  = tid & 63;
  const int lr    = lane & 15;
  const int lg    = lane >> 4;

  __shared__ __align__(16) ushort_t Is[16 * 512];   // fragment-major
  __shared__ __align__(16) ushort_t Hs[16 * 512];   // fragment-major
  __shared__ __align__(16) float gates[4][16][16];
  __shared__ __align__(16) ull raw[2048 * 2];       // async ring landing (32KB), XOR-swz slots

  const int NI  = layer ? 16 : 8;
  const int Din = layer ? HDIM : DDIM;
  const float* wih = layer ? w_ih1 : w_ih0;
  const float* whh = layer ? w_hh1 : w_hh0;
  const float* bb  = layer ? b1 : b0;
  const int grow = wv * HDIM + ct * 16 + lr;

  short8 wf[32];
#pragma unroll
  for (int kf = 0; kf < 32; ++kf) wf[kf] = (short8)((short)0);
#pragma unroll
  for (int kf = 0; kf < 32; ++kf) {
    if (kf < NI + 16) {
      const float* src;
      if (kf < NI) src = wih + (size_t)grow * Din + (size_t)kf * 32 + lg * 8;
      else         src = whh + (size_t)grow * HDIM + (size_t)(kf - NI) * 32 + lg * 8;
      float4 a = *(const float4*)(src);
      float4 bq = *(const float4*)(src + 4);
      wf[kf] = pack8(a, bq);
    }
  }
  const float bias = bb[grow];

  float c4[4] = {0.f, 0.f, 0.f, 0.f};     // wave0: 4 cell states
  float4 xp0, xp1, xp2, xp3;               // layer0: x prefetch
  const int xr = tid >> 4;
  const int xcb = tid & 15;
  const int s_ = tid & 15, h_ = (tid >> 4) & 3;

  if (layer == 0) {
    const float4* xv = (const float4*)(x + (size_t)(bt * 16 + xr) * (TDIM * DDIM) + xcb * 16);
    xp0 = xv[0]; xp1 = xv[1]; xp2 = xv[2]; xp3 = xv[3];
  }

  for (int t = 0; t < TDIM; ++t) {
    // ---- P1: only layer0 wave1 polls ring back-pressure (off-critical) ----
    if (layer == 0 && wv == 1 && t >= RING)
      wave_poll_sc1(consF + bt * 32 + (lane & 31), (uint32)(t - RING + 1));

    // ---- P2/P3: stage Is; issue async ring[t+1]; h spin + stage Hs ----
    if (layer == 0) {
      {
        const int c0 = xcb * 16;
        *(short8*)&Is[frag_off(xr, c0 >> 5, (c0 >> 3) & 3)] = pack8(xp0, xp1);
        const int c1 = c0 + 8;
        *(short8*)&Is[frag_off(xr, c1 >> 5, (c1 >> 3) & 3)] = pack8(xp2, xp3);
      }
      if (t > 0) {
        ull hv[8];
        load_tagged_8(ringT + (size_t)((t - 1) & (RING - 1)) * SLOT_BYTES
                      + (size_t)bt * BT_BYTES, tid, (uint32)t, hv);
        ds_stage(Hs, tid, hv);
      }
    } else {
      // -- consume ring[t]: t==0 blocking; t>0 from async raw (tag-checked) --
      if (t == 0) {
        ull rv[8];
        load_tagged_8(ringT + (size_t)bt * BT_BYTES, tid, 1u, rv);
        ds_stage(Is, tid, rv);
      } else {
        asm volatile("s_waitcnt vmcnt(0)" ::: "memory");   // drain own async loads
        ull hv8[8];
        int okm = 1;
        const uint32 expect = (uint32)(t + 1);
        const int c_lo = (((s_ >> 1) & 7) * 8) + h_ * 2 + (s_ & 1);
#pragma unroll
        for (int q = 0; q < 8; ++q) {
          const int row = wv * 4 + (q & 3);
          const int G = row * 128 + ((q >> 2) << 6) + c_lo;
          const int i = G ^ ((G >> 3) & 7);
          u32x4 cc = *(const u32x4*)&raw[(size_t)i * 2];
          hv8[q] = ((ull)cc.y << 32) | cc.x;
          okm &= (int)(cc.z == expect);
        }
        if (!okm)   // async raced producer or stale: blocking fallback (rare)
          load_tagged_8(ringT + (size_t)(t & (RING - 1)) * SLOT_BYTES
                        + (size_t)bt * BT_BYTES, tid, expect, hv8);
        ds_stage(Is, tid, hv8);
      }
      // -- issue async loads for ring[t+1] (fire-and-forget; drained next step) --
      if (t + 1 < TDIM) {
        const char* slot = ringT + (size_t)((t + 1) & (RING - 1)) * SLOT_BYTES
                         + (size_t)bt * BT_BYTES;
#pragma unroll
        for (int j = 0; j < 8; ++j) {
          const int i = wv * 512 + j * 64 + lane;
          const int G = i ^ ((i >> 3) & 7);   // involution: source pre-swizzle
          __builtin_amdgcn_global_load_lds(
              (const __attribute__((address_space(1))) uint32*)(slot + (size_t)G * 16),
              (__attribute__((address_space(3))) uint32*)&raw[(size_t)(wv * 512 + j * 64) * 2],
              16, 0, 17 /* sc0|sc1 */);
        }
      }
      // -- h1 chain spin (the true recurrence dependency) --
      if (t > 0) {
        ull hv[8];
        load_tagged_8(h1T + (size_t)((t - 1) & 1) * SLOT_BYTES
                      + (size_t)bt * BT_BYTES, tid, (uint32)t, hv);
        ds_stage(Hs, tid, hv);
      }
    }
    __syncthreads();   // B1: tiles complete
    if (layer == 1 && tid == 0)
      st_sc1(consF + bt * 32 + ct, (uint32)(t + 1));   // slots <= t consumed

    // ---- P5: MFMA (conflict-free fragment reads) ----
    f32x4 acc0 = {0.f, 0.f, 0.f, 0.f}, acc1 = {0.f, 0.f, 0.f, 0.f};
#pragma unroll
    for (int kf = 0; kf < 16; ++kf) {
      if (kf < NI) {
        const short8 af = *(const short8*)&Is[frag_off(lr, kf, lg)];
        if (kf & 1) acc1 = __builtin_amdgcn_mfma_f32_16x16x32_bf16(af, wf[kf], acc1, 0, 0, 0);
        else        acc0 = __builtin_amdgcn_mfma_f32_16x16x32_bf16(af, wf[kf], acc0, 0, 0, 0);
      }
    }
    if (t > 0) {
#pragma unroll
      for (int kf = 0; kf < 16; ++kf) {
        const short8 af = *(const short8*)&Hs[frag_off(lr, kf, lg)];
        if (kf & 1) acc1 = __builtin_amdgcn_mfma_f32_16x16x32_bf16(af, wf[NI + kf], acc1, 0, 0, 0);
        else        acc0 = __builtin_amdgcn_mfma_f32_16x16x32_bf16(af, wf[NI + kf], acc0, 0, 0, 0);
      }
    }
#pragma unroll
    for (int i = 0; i < 4; ++i) {
      float v = acc0[i] + acc1[i] + bias;
      float a = (wv < 3) ? sigm(v) : tanh_fast(v);
      gates[wv][lg * 4 + i][lr] = a;
    }
    __syncthreads();   // B2: gates complete (also fences Hs/Is reuse)

    // ---- P6/P7: pointwise (wave0) + tagged publish; L0 others prefetch x ----
    if (layer == 0 && wv != 0 && t + 1 < TDIM) {
      const float4* xv = (const float4*)(x + (size_t)(bt * 16 + xr) * (TDIM * DDIM)
                                           + (size_t)(t + 1) * DDIM + xcb * 16);
      xp0 = xv[0]; xp1 = xv[1]; xp2 = xv[2]; xp3 = xv[3];
    }
    if (wv == 0) {
      const int r  = lane >> 2;
      const int cg = lane & 3;
      f32x4 gi = *(const f32x4*)&gates[0][r][cg * 4];
      f32x4 gf = *(const f32x4*)&gates[1][r][cg * 4];
      f32x4 go = *(const f32x4*)&gates[2][r][cg * 4];
      f32x4 gg = *(const f32x4*)&gates[3][r][cg * 4];
      f32x4 nh4, nc4;
#pragma unroll
      for (int k = 0; k < 4; ++k) {
        float nc = gf[k] * c4[k] + gi[k] * gg[k];
        float nh = go[k] * tanh_fast(nc);     // h uses UNCLIPPED c
        nc = fminf(fmaxf(nc, -50.f), 50.f);
        nh = fminf(fmaxf(nh, -50.f), 50.f);
        c4[k] = nc; nh4[k] = nh; nc4[k] = nc;
      }
      const ull hv = pack4bf(nh4);
      // tagged publish: ONE 16B store, no ack, no flag.
      u32x4 pub;
      pub.x = (uint32)hv; pub.y = (uint32)(hv >> 32);
      pub.z = (uint32)(t + 1); pub.w = 0u;
      char* dst = (layer == 0)
          ? ringT + (size_t)(t & (RING - 1)) * SLOT_BYTES + (size_t)bt * BT_BYTES
          : h1T + (size_t)(t & 1) * SLOT_BYTES + (size_t)bt * BT_BYTES;
      dst += (size_t)r * 2048 + (size_t)(ct * 4 + cg) * 16;
      asm volatile("global_store_dwordx4 %0, %1, off sc0 sc1"
                   :: "v"(dst), "v"(pub) : "memory");
      if (layer == 1)
        *(f32x4*)&out[(size_t)(bt * 16 + r) * (TDIM * HDIM) + (size_t)t * HDIM + ct * 16 + cg * 4] = nh4;
      if (t == TDIM - 1) {
        const size_t OH = (size_t)BDIM * TDIM * HDIM;
        const size_t OC = OH + 2 * (size_t)BDIM * HDIM;
        *(f32x4*)&out[OH + (size_t)layer * BDIM * HDIM + (size_t)(bt * 16 + r) * HDIM + ct * 16 + cg * 4] = nh4;
        *(f32x4*)&out[OC + (size_t)layer * BDIM * HDIM + (size_t)(bt * 16 + r) * HDIM + ct * 16 + cg * 4] = nc4;
      }
      if (layer == 0 && t + 1 < TDIM) {
        const float4* xv = (const float4*)(x + (size_t)(bt * 16 + xr) * (TDIM * DDIM)
                                             + (size_t)(t + 1) * DDIM + xcb * 16);
        xp0 = xv[0]; xp1 = xv[1]; xp2 = xv[2]; xp3 = xv[3];
      }
    }
  }
}

extern "C" void kernel_launch(void* const* d_in, const int* in_sizes, int n_in,
                              void* d_out, int out_size, void* d_ws, size_t ws_size,
                              hipStream_t stream) {
  (void)in_sizes; (void)n_in; (void)out_size; (void)ws_size;
  const float* x     = (const float*)d_in[0];
  const float* w_ih0 = (const float*)d_in[1];
  const float* w_hh0 = (const float*)d_in[2];
  const float* b0    = (const float*)d_in[3];
  const float* w_ih1 = (const float*)d_in[4];
  const float* w_hh1 = (const float*)d_in[5];
  const float* b1    = (const float*)d_in[6];
  float* out = (float*)d_out;

  char* ws = (char*)d_ws;
  uint32* consF = (uint32*)(ws + 0);                 // [4][32]
  char* ringT = ws + 8192;                           // 4 slots x 4bt x 32KB = 512KB tagged
  char* h1T   = ws + 8192 + 4 * SLOT_BYTES;          // 2 par  x 4bt x 32KB = 256KB tagged

  // memset EVERY launch: resets tags (replay-safe) + consF
  hipMemsetAsync(ws, 0, 8192, stream);
  hipMemsetAsync(ws + 8192, 0, 6 * SLOT_BYTES, stream);
  lstm_fused<<<dim3(256), dim3(256), 0, stream>>>(
      x, w_ih0, w_hh0, b0, w_ih1, w_hh1, b1, out, consF, ringT, h1T);
}

// Round 23
// 2509.192 us; speedup vs baseline: 1.1730x; 1.1730x over previous
//
#include <hip/hip_runtime.h>

#define BDIM 64
#define TDIM 1024
#define DDIM 256
#define HDIM 512
#define RING 4

typedef unsigned short ushort_t;
typedef unsigned int uint32;
typedef unsigned long long ull;
typedef __attribute__((ext_vector_type(8))) short short8;
typedef __attribute__((ext_vector_type(4))) float f32x4;
typedef __attribute__((ext_vector_type(4))) uint32 u32x4;

__device__ __forceinline__ ushort_t f2bf(float f) {
  union { float f; uint32 u; } v; v.f = f;
  uint32 u = v.u;
  return (ushort_t)((u + 0x7fffu + ((u >> 16) & 1u)) >> 16);
}

__device__ __forceinline__ short8 pack8(float4 a, float4 b) {
  short8 s;
  s[0] = (short)f2bf(a.x); s[1] = (short)f2bf(a.y);
  s[2] = (short)f2bf(a.z); s[3] = (short)f2bf(a.w);
  s[4] = (short)f2bf(b.x); s[5] = (short)f2bf(b.y);
  s[6] = (short)f2bf(b.z); s[7] = (short)f2bf(b.w);
  return s;
}

__device__ __forceinline__ ull pack4bf(f32x4 v) {
  return (ull)f2bf(v[0]) | ((ull)f2bf(v[1]) << 16)
       | ((ull)f2bf(v[2]) << 32) | ((ull)f2bf(v[3]) << 48);
}

__device__ __forceinline__ float sigm(float x) { return 1.0f / (1.0f + __expf(-x)); }
__device__ __forceinline__ float tanh_fast(float x) { return 1.0f - 2.0f / (__expf(2.0f * x) + 1.0f); }

__device__ __forceinline__ uint32 ld_sc1(uint32* p) {
  return __hip_atomic_load(p, __ATOMIC_RELAXED, __HIP_MEMORY_SCOPE_AGENT);
}
__device__ __forceinline__ void st_sc1(uint32* p, uint32 v) {
  __hip_atomic_store(p, v, __ATOMIC_RELAXED, __HIP_MEMORY_SCOPE_AGENT);
}

__device__ __forceinline__ void wave_poll_sc1(uint32* fl, uint32 tgt) {
  int it = 0;
  for (;;) {
    uint32 v = ld_sc1(fl);
    if (__all((int)(v >= tgt))) break;
    __builtin_amdgcn_s_sleep(1);
    if (++it > 60000) break;   // bounded: wrong beats hang
  }
  asm volatile("" ::: "memory");
}

// ---- fragment-major LDS layout (conflict-free MFMA reads, r10/r14-proven) ----
__device__ __forceinline__ int frag_off(int row, int kf, int lg) {   // ushort units
  return kf * 512 + (((lg * 16 + row) ^ (kf & 7)) << 3);
}

// ---- r14 lane-permuted staging map: conflict-free b64 LDS writes ----
__device__ __forceinline__ void ds_stage(ushort_t* dst, int tid, const ull* v) {
  const int s = tid & 15, h = (tid >> 4) & 3, wvq = tid >> 6;
#pragma unroll
  for (int q = 0; q < 8; ++q) {
    const int row = wvq * 4 + (q & 3);
    const int kf  = ((q >> 2) << 3) | ((s >> 1) & 7);
    *(ull*)&dst[frag_off(row, kf, h) + (s & 1) * 4] = v[q];
  }
}

// chunk offset within a bt tile for this thread (r14 index space, 16B chunks)
__device__ __forceinline__ size_t chunk_off(int tid) {
  const int s = tid & 15, h = (tid >> 4) & 3, wvq = tid >> 6;
  return (size_t)(wvq * 4) * 2048
       + (size_t)(((((s >> 1) & 7) * 8) + h * 2 + (s & 1)) * 16);
}

// ---- tag-fused tile load: 16B chunks [h:8B][tag:4B][pad:4B], spin per-thread ----
// q-th chunk addr = base + (q&3)*2048 + (q>>2)*1024. Offsets {0,1024,2048,3072}
// from {base, base+4096} cover q = {0,4,1,5, 2,6,3,7}.
__device__ __forceinline__ void load_tagged_8(const char* buf, int tid, uint32 expect, ull* v) {
  const char* base  = buf + chunk_off(tid);
  const char* base2 = base + 4096;
  u32x4 c0, c1, c2, c3, c4v, c5, c6, c7;
  int it = 0;
  for (;;) {
    asm volatile(
        "global_load_dwordx4 %0, %8, off sc0 sc1\n\t"
        "global_load_dwordx4 %1, %8, off offset:1024 sc0 sc1\n\t"
        "global_load_dwordx4 %2, %8, off offset:2048 sc0 sc1\n\t"
        "global_load_dwordx4 %3, %8, off offset:3072 sc0 sc1\n\t"
        "global_load_dwordx4 %4, %9, off sc0 sc1\n\t"
        "global_load_dwordx4 %5, %9, off offset:1024 sc0 sc1\n\t"
        "global_load_dwordx4 %6, %9, off offset:2048 sc0 sc1\n\t"
        "global_load_dwordx4 %7, %9, off offset:3072 sc0 sc1\n\t"
        "s_waitcnt vmcnt(0)"
        : "=&v"(c0), "=&v"(c1), "=&v"(c2), "=&v"(c3),
          "=&v"(c4v), "=&v"(c5), "=&v"(c6), "=&v"(c7)
        : "v"(base), "v"(base2) : "memory");
    bool ok = (c0.z == expect) & (c1.z == expect) & (c2.z == expect) & (c3.z == expect)
            & (c4v.z == expect) & (c5.z == expect) & (c6.z == expect) & (c7.z == expect);
    if (ok) break;
    if (++it > 30000) break;   // bounded: wrong beats hang
  }
  v[0] = ((ull)c0.y << 32) | c0.x;   v[4] = ((ull)c1.y << 32) | c1.x;
  v[1] = ((ull)c2.y << 32) | c2.x;   v[5] = ((ull)c3.y << 32) | c3.x;
  v[2] = ((ull)c4v.y << 32) | c4v.x; v[6] = ((ull)c5.y << 32) | c5.x;
  v[3] = ((ull)c6.y << 32) | c6.x;   v[7] = ((ull)c7.y << 32) | c7.x;
}

#define BT_BYTES   32768            // 16 rows x 128 chunks x 16B
#define SLOT_BYTES (4 * BT_BYTES)   // 4 bt tiles

__global__ void __launch_bounds__(256, 1)
lstm_fused(const float* __restrict__ x,
           const float* __restrict__ w_ih0, const float* __restrict__ w_hh0,
           const float* __restrict__ b0,
           const float* __restrict__ w_ih1, const float* __restrict__ w_hh1,
           const float* __restrict__ b1,
           float* __restrict__ out,
           uint32* consF, char* ringT, char* h1T)
{
  const int b     = (int)blockIdx.x;
  const int g     = b & 7;
  const int layer = g >> 2;
  const int bt    = g & 3;
  const int ct    = b >> 3;
  const int tid   = (int)threadIdx.x;
  const int wv    = tid >> 6;
  const int lane  = tid & 63;
  const int lr    = lane & 15;
  const int lg    = lane >> 4;

  __shared__ __align__(16) ushort_t Is[16 * 512];   // fragment-major
  __shared__ __align__(16) ushort_t Hs[16 * 512];   // fragment-major
  __shared__ __align__(16) float gates[4][16][16];

  const int NI  = layer ? 16 : 8;
  const int Din = layer ? HDIM : DDIM;
  const float* wih = layer ? w_ih1 : w_ih0;
  const float* whh = layer ? w_hh1 : w_hh0;
  const float* bb  = layer ? b1 : b0;
  const int grow = wv * HDIM + ct * 16 + lr;

  short8 wf[32];
#pragma unroll
  for (int kf = 0; kf < 32; ++kf) wf[kf] = (short8)((short)0);
#pragma unroll
  for (int kf = 0; kf < 32; ++kf) {
    if (kf < NI + 16) {
      const float* src;
      if (kf < NI) src = wih + (size_t)grow * Din + (size_t)kf * 32 + lg * 8;
      else         src = whh + (size_t)grow * HDIM + (size_t)(kf - NI) * 32 + lg * 8;
      float4 a = *(const float4*)(src);
      float4 bq = *(const float4*)(src + 4);
      wf[kf] = pack8(a, bq);
    }
  }
  const float bias = bb[grow];

  float c4[4] = {0.f, 0.f, 0.f, 0.f};     // wave0: 4 cell states
  float4 xp0, xp1, xp2, xp3;               // layer0: x prefetch
  ull rv[8];                               // layer1: ring tile prefetch (regs)
  const int xr = tid >> 4;
  const int xcb = tid & 15;

  if (layer == 0) {
    const float4* xv = (const float4*)(x + (size_t)(bt * 16 + xr) * (TDIM * DDIM) + xcb * 16);
    xp0 = xv[0]; xp1 = xv[1]; xp2 = xv[2]; xp3 = xv[3];
  } else {
    // prologue prefetch: ring[0] (tag 1)
    load_tagged_8(ringT + (size_t)bt * BT_BYTES, tid, 1u, rv);
  }

  for (int t = 0; t < TDIM; ++t) {
    // ---- P1: only layer0 wave1 polls ring back-pressure (off-critical) ----
    if (layer == 0 && wv == 1 && t >= RING)
      wave_poll_sc1(consF + bt * 32 + (lane & 31), (uint32)(t - RING + 1));

    // ---- P2/P3: tag-fused h load + stage (ring comes from prefetch regs) ----
    if (layer == 0) {
      {
        const int c0 = xcb * 16;
        *(short8*)&Is[frag_off(xr, c0 >> 5, (c0 >> 3) & 3)] = pack8(xp0, xp1);
        const int c1 = c0 + 8;
        *(short8*)&Is[frag_off(xr, c1 >> 5, (c1 >> 3) & 3)] = pack8(xp2, xp3);
      }
      if (t > 0) {
        ull hv[8];
        load_tagged_8(ringT + (size_t)((t - 1) & (RING - 1)) * SLOT_BYTES
                      + (size_t)bt * BT_BYTES, tid, (uint32)t, hv);
        ds_stage(Hs, tid, hv);
      }
    } else {
      ds_stage(Is, tid, rv);    // ring[t], prefetched at end of step t-1
      if (t > 0) {
        ull hv[8];
        load_tagged_8(h1T + (size_t)((t - 1) & 1) * SLOT_BYTES
                      + (size_t)bt * BT_BYTES, tid, (uint32)t, hv);
        ds_stage(Hs, tid, hv);
      }
    }
    __syncthreads();   // B1: tiles complete
    if (layer == 1 && tid == 0)
      st_sc1(consF + bt * 32 + ct, (uint32)(t + 1));   // slots <= t consumed

    // ---- P5: MFMA (conflict-free fragment reads) ----
    f32x4 acc0 = {0.f, 0.f, 0.f, 0.f}, acc1 = {0.f, 0.f, 0.f, 0.f};
#pragma unroll
    for (int kf = 0; kf < 16; ++kf) {
      if (kf < NI) {
        const short8 af = *(const short8*)&Is[frag_off(lr, kf, lg)];
        if (kf & 1) acc1 = __builtin_amdgcn_mfma_f32_16x16x32_bf16(af, wf[kf], acc1, 0, 0, 0);
        else        acc0 = __builtin_amdgcn_mfma_f32_16x16x32_bf16(af, wf[kf], acc0, 0, 0, 0);
      }
    }
    if (t > 0) {
#pragma unroll
      for (int kf = 0; kf < 16; ++kf) {
        const short8 af = *(const short8*)&Hs[frag_off(lr, kf, lg)];
        if (kf & 1) acc1 = __builtin_amdgcn_mfma_f32_16x16x32_bf16(af, wf[NI + kf], acc1, 0, 0, 0);
        else        acc0 = __builtin_amdgcn_mfma_f32_16x16x32_bf16(af, wf[NI + kf], acc0, 0, 0, 0);
      }
    }
#pragma unroll
    for (int i = 0; i < 4; ++i) {
      float v = acc0[i] + acc1[i] + bias;
      float a = (wv < 3) ? sigm(v) : tanh_fast(v);
      gates[wv][lg * 4 + i][lr] = a;
    }
    __syncthreads();   // B2: gates complete (also fences Hs/Is reuse)

    // ---- P6/P7: pointwise (wave0) + tagged publish; others prefetch ----
    if (layer == 0 && wv != 0 && t + 1 < TDIM) {
      const float4* xv = (const float4*)(x + (size_t)(bt * 16 + xr) * (TDIM * DDIM)
                                           + (size_t)(t + 1) * DDIM + xcb * 16);
      xp0 = xv[0]; xp1 = xv[1]; xp2 = xv[2]; xp3 = xv[3];
    }
    if (layer == 1 && wv != 0 && t + 1 < TDIM) {
      // ring[t+1] prefetch (usually first-try: layer0 runs ahead)
      load_tagged_8(ringT + (size_t)((t + 1) & (RING - 1)) * SLOT_BYTES
                    + (size_t)bt * BT_BYTES, tid, (uint32)(t + 2), rv);
    }
    if (wv == 0) {
      const int r  = lane >> 2;
      const int cg = lane & 3;
      f32x4 gi = *(const f32x4*)&gates[0][r][cg * 4];
      f32x4 gf = *(const f32x4*)&gates[1][r][cg * 4];
      f32x4 go = *(const f32x4*)&gates[2][r][cg * 4];
      f32x4 gg = *(const f32x4*)&gates[3][r][cg * 4];
      f32x4 nh4, nc4;
#pragma unroll
      for (int k = 0; k < 4; ++k) {
        float nc = gf[k] * c4[k] + gi[k] * gg[k];
        float nh = go[k] * tanh_fast(nc);     // h uses UNCLIPPED c
        nc = fminf(fmaxf(nc, -50.f), 50.f);
        nh = fminf(fmaxf(nh, -50.f), 50.f);
        c4[k] = nc; nh4[k] = nh; nc4[k] = nc;
      }
      const ull hv = pack4bf(nh4);
      // tagged publish: ONE 16B store, no ack, no flag. The wave's own next
      // tag-spin s_waitcnt vmcnt(0) drains it (same-address ordering safe).
      u32x4 pub;
      pub.x = (uint32)hv; pub.y = (uint32)(hv >> 32);
      pub.z = (uint32)(t + 1); pub.w = 0u;
      char* dst = (layer == 0)
          ? ringT + (size_t)(t & (RING - 1)) * SLOT_BYTES + (size_t)bt * BT_BYTES
          : h1T + (size_t)(t & 1) * SLOT_BYTES + (size_t)bt * BT_BYTES;
      dst += (size_t)r * 2048 + (size_t)(ct * 4 + cg) * 16;
      asm volatile("global_store_dwordx4 %0, %1, off sc0 sc1"
                   :: "v"(dst), "v"(pub) : "memory");
      if (layer == 1)
        *(f32x4*)&out[(size_t)(bt * 16 + r) * (TDIM * HDIM) + (size_t)t * HDIM + ct * 16 + cg * 4] = nh4;
      if (t == TDIM - 1) {
        const size_t OH = (size_t)BDIM * TDIM * HDIM;
        const size_t OC = OH + 2 * (size_t)BDIM * HDIM;
        *(f32x4*)&out[OH + (size_t)layer * BDIM * HDIM + (size_t)(bt * 16 + r) * HDIM + ct * 16 + cg * 4] = nh4;
        *(f32x4*)&out[OC + (size_t)layer * BDIM * HDIM + (size_t)(bt * 16 + r) * HDIM + ct * 16 + cg * 4] = nc4;
      }
      if (layer == 0 && t + 1 < TDIM) {
        const float4* xv = (const float4*)(x + (size_t)(bt * 16 + xr) * (TDIM * DDIM)
                                             + (size_t)(t + 1) * DDIM + xcb * 16);
        xp0 = xv[0]; xp1 = xv[1]; xp2 = xv[2]; xp3 = xv[3];
      }
      if (layer == 1 && t + 1 < TDIM) {   // wave0's own ring prefetch, after publish
        load_tagged_8(ringT + (size_t)((t + 1) & (RING - 1)) * SLOT_BYTES
                      + (size_t)bt * BT_BYTES, tid, (uint32)(t + 2), rv);
      }
    }
  }
}

extern "C" void kernel_launch(void* const* d_in, const int* in_sizes, int n_in,
                              void* d_out, int out_size, void* d_ws, size_t ws_size,
                              hipStream_t stream) {
  (void)in_sizes; (void)n_in; (void)out_size; (void)ws_size;
  const float* x     = (const float*)d_in[0];
  const float* w_ih0 = (const float*)d_in[1];
  const float* w_hh0 = (const float*)d_in[2];
  const float* b0    = (const float*)d_in[3];
  const float* w_ih1 = (const float*)d_in[4];
  const float* w_hh1 = (const float*)d_in[5];
  const float* b1    = (const float*)d_in[6];
  float* out = (float*)d_out;

  char* ws = (char*)d_ws;
  uint32* consF = (uint32*)(ws + 0);                 // [4][32]
  char* ringT = ws + 8192;                           // 4 slots x 4bt x 32KB = 512KB tagged
  char* h1T   = ws + 8192 + 4 * SLOT_BYTES;          // 2 par  x 4bt x 32KB = 256KB tagged

  // memset EVERY launch: resets tags (replay-safe) + consF
  hipMemsetAsync(ws, 0, 8192, stream);
  hipMemsetAsync(ws + 8192, 0, 6 * SLOT_BYTES, stream);
  lstm_fused<<<dim3(256), dim3(256), 0, stream>>>(
      x, w_ih0, w_hh0, b0, w_ih1, w_hh1, b1, out, consF, ringT, h1T);
}